// Round 4
// baseline (649.455 us; speedup 1.0000x reference)
//
#include <hip/hip_runtime.h>
#include <hip/hip_bf16.h>

// SparseMLP: per-expert  out = gelu_tanh(x @ w1^T) @ w2
// E=8, T=2048, H=1024, F=4096. fp32 in/out, bf16 MFMA compute.
//
// R3: 128^2 gemm_bt ~200us/GEMM. R4: lockstep 8-barrier 256^2 FAILED (239us).
// R6: GEMM1 = gemm_bt + VALU diet -> 187.5us (VGPR 60, occ 41%);
//     GEMM2 = gemm_ra (256^2 read-ahead, 2 barriers/kt, counted vmcnt)
//     ~170us (est; dropped out of top-5).
// Model (R6 counters): MfmaUtil 33 == computed matrix-pipe busy (54.6us of
//     matrix work per 188us dispatch). Bank conflicts (16.8M = +4cy/b128)
//     cost only ~27us of a 30%-utilized LDS pipe -> NOT binding (m252
//     regime lesson). Binding: matrix-pipe idle from per-kt latency
//     exposure under the barrier structure.
// R7 (this): follow measured gradient -- GEMM1 ported to gemm_ra too
//     (GELU/bf16 epilogue via existing template). GEMM2 + preamble frozen.
//     Also makes both GEMMs visible in top-5 counters next round.

typedef __bf16 bf16x8 __attribute__((ext_vector_type(8)));
typedef float  f32x16 __attribute__((ext_vector_type(16)));

__device__ inline unsigned short f2b(float f) {
    unsigned u = __float_as_uint(f);
    u += 0x7fff + ((u >> 16) & 1);   // round-to-nearest-even
    return (unsigned short)(u >> 16);
}

// ---------------- fused cast fp32 -> bf16 for two arrays ----------------
__global__ void cast2_f32_bf16(const float* __restrict__ a,
                               unsigned short* __restrict__ oa, int na4,
                               const float* __restrict__ b,
                               unsigned short* __restrict__ ob, int nb4) {
    int i = blockIdx.x * 256 + threadIdx.x;
    const float4* src;
    ushort4* dst;
    if (i < na4) {
        src = (const float4*)a + i;
        dst = (ushort4*)oa + i;
    } else {
        i -= na4;
        if (i >= nb4) return;
        src = (const float4*)b + i;
        dst = (ushort4*)ob + i;
    }
    float4 v = *src;
    ushort4 o;
    o.x = f2b(v.x); o.y = f2b(v.y); o.z = f2b(v.z); o.w = f2b(v.w);
    *dst = o;
}

// ------------- transpose-cast w2: fp32 [E,F,H] -> bf16 [E,H,F] -------------
__global__ void transpose_cast(const float* __restrict__ in,
                               unsigned short* __restrict__ out, int F, int H) {
    __shared__ float tile[64][33];
    const int e = blockIdx.z;
    const int f0 = blockIdx.y * 64, h0 = blockIdx.x * 32;
    const float* src = in + (long long)e * F * H;
    unsigned short* dst = out + (long long)e * F * H;
    const int tx = threadIdx.x, ty = threadIdx.y;   // 32 x 8
#pragma unroll
    for (int i = 0; i < 64; i += 8)
        tile[ty + i][tx] = src[(long long)(f0 + ty + i) * H + h0 + tx];
    __syncthreads();
#pragma unroll
    for (int i = 0; i < 32; i += 8) {
        const int h = ty + i;
        ushort2 o;
        o.x = f2b(tile[2 * tx][h]);
        o.y = f2b(tile[2 * tx + 1][h]);
        *(ushort2*)&dst[(long long)(h0 + h) * F + f0 + 2 * tx] = o;
    }
}

// ---------------- GEMM: 256^2 read-ahead, 2 barriers/kt ----------
// A:[E][M][K], B:[E][N][K] bf16 K-major; C = CT. 512 thr = 8 waves (2M x 4N),
// wave owns 128x64 (4 msub x 2 nsub of 32x32). LDS 128KB double-buffered.
// Schedule per kt (verified R6, passed):
//   P1: lgk0; MFMA(af x bf0); read bf1; STG A(kt+1) q0,q1
//   P2: lgk0; MFMA(af x bf1); STG A(kt+1) q2,q3; barrier
//   P3: reload af(qm1); STG B(kt+2) q0,q1; lgk0; MFMA(af x bf0)
//   P4: MFMA(af x bf1); STG B(kt+2) q2,q3; vmcnt(4); barrier
//   Pb: read af(qm0)+bf0 for kt+1 from buf p^1
// Hazards: sA[p^1] WAR drained by kt-1 P3 lgk0 < P4 barrier < P1 STG;
//   sB[p] WAR drained by P2-entry lgk0 < P2 barrier < P3 STG; RAW of
//   A(kt+1),B(kt+1) drained by boundary vmcnt(4) (only B(kt+2) in flight).
#define STG(dst, ptr, q)                                                      \
    __builtin_amdgcn_global_load_lds(                                         \
        (const __attribute__((address_space(1))) void*)(ptr),                 \
        (__attribute__((address_space(3))) void*)(&(dst)[(q) * 4096 + sdst]), \
        16, 0, 0)
#define LGK0 do { asm volatile("s_waitcnt lgkmcnt(0)" ::: "memory");          \
                  __builtin_amdgcn_sched_barrier(0); } while (0)

template <bool GELU, typename CT>
__global__ __launch_bounds__(512) void gemm_ra(
    const unsigned short* __restrict__ A,
    const unsigned short* __restrict__ B,
    CT* __restrict__ C, int M, int N, int K) {
    // XCD-chunked bijective raster (nwg % 8 == 0)
    const int nwg = gridDim.x;
    const int id = blockIdx.x;
    const int wgid = (id & 7) * (nwg >> 3) + (id >> 3);
    const int ntn = N >> 8;
    const int tpe = (M >> 8) * ntn;
    const int e = wgid / tpe;
    const int rem = wgid - e * tpe;
    const int bm = (rem / ntn) << 8;
    const int bn = (rem % ntn) << 8;
    A += (long long)e * M * K;
    B += (long long)e * N * K;
    C += (long long)e * M * N;

    __shared__ __align__(16) unsigned short sA[2][16384];
    __shared__ __align__(16) unsigned short sB[2][16384];

    const int tid = threadIdx.x;
    const int lane = tid & 63;
    const int wid = tid >> 6;
    const int half = lane >> 5, r32 = lane & 31;
    const int wm = (wid >> 2) * 128;
    const int wn = (wid & 3) * 64;

    const int srow = tid >> 3;                             // 0..63
    const int scol = ((tid & 7) ^ ((tid >> 3) & 7)) << 3;  // swizzled src col
    const int sdst = tid * 8;

    // staging cursors: pA -> kt+1 columns, pB -> kt+2 columns
    const unsigned short* pA[4];
    const unsigned short* pB[4];
#pragma unroll
    for (int q = 0; q < 4; ++q) {
        pA[q] = A + (long long)(bm + q * 64 + srow) * K + scol;
        pB[q] = B + (long long)(bn + q * 64 + srow) * K + scol;
    }
    const int NT = K >> 6;

    // ---- prologue: stage A(0), B(0), B(1); leave B(1) in flight (vmcnt 4)
    STG(sA[0], pA[0], 0); STG(sA[0], pA[1], 1);
    STG(sA[0], pA[2], 2); STG(sA[0], pA[3], 3);
    STG(sB[0], pB[0], 0); STG(sB[0], pB[1], 1);
    STG(sB[0], pB[2], 2); STG(sB[0], pB[3], 3);
    if (NT > 1) {
#pragma unroll
        for (int q = 0; q < 4; ++q) STG(sB[1], pB[q] + 64, q);
        asm volatile("s_waitcnt vmcnt(4)" ::: "memory");
    } else {
        asm volatile("s_waitcnt vmcnt(0)" ::: "memory");
    }
#pragma unroll
    for (int q = 0; q < 4; ++q) { pA[q] += 64; pB[q] += 128; }
    __builtin_amdgcn_s_barrier();

    f32x16 acc[4][2] = {};
    bf16x8 af[2][4], bf0[4], bf1[4];

    // ---- Pb(prologue): read af(qm0) + bf0 for kt=0
#pragma unroll
    for (int m = 0; m < 2; ++m) {
        const int row = wm + m * 32 + r32;
#pragma unroll
        for (int ks = 0; ks < 4; ++ks)
            af[m][ks] = *(const bf16x8*)
                &sA[0][row * 64 + (((ks * 2 + half) ^ (row & 7)) << 3)];
    }
    {
        const int row = wn + r32;
#pragma unroll
        for (int ks = 0; ks < 4; ++ks)
            bf0[ks] = *(const bf16x8*)
                &sB[0][row * 64 + (((ks * 2 + half) ^ (row & 7)) << 3)];
    }

    for (int kt = 0; kt < NT; ++kt) {
        const int p = kt & 1;
        const bool pfA = (kt + 1 < NT), pfB = (kt + 2 < NT);
        unsigned short* nA = sA[p ^ 1];
        unsigned short* stB = sB[p];

        // ---- P1: MFMA(af x bf0 -> acc[0..1][0]); read bf1; STG A q0,q1
        LGK0;
        __builtin_amdgcn_s_setprio(1);
#pragma unroll
        for (int ks = 0; ks < 4; ++ks)
#pragma unroll
            for (int m = 0; m < 2; ++m)
                acc[m][0] = __builtin_amdgcn_mfma_f32_32x32x16_bf16(
                    af[m][ks], bf0[ks], acc[m][0], 0, 0, 0);
        __builtin_amdgcn_s_setprio(0);
        {
            const int row = wn + 32 + r32;
#pragma unroll
            for (int ks = 0; ks < 4; ++ks)
                bf1[ks] = *(const bf16x8*)
                    &sB[p][row * 64 + (((ks * 2 + half) ^ (row & 7)) << 3)];
        }
        if (pfA) { STG(nA, pA[0], 0); STG(nA, pA[1], 1); }

        // ---- P2: MFMA(af x bf1 -> acc[0..1][1]); STG A q2,q3; barrier
        LGK0;
        __builtin_amdgcn_s_setprio(1);
#pragma unroll
        for (int ks = 0; ks < 4; ++ks)
#pragma unroll
            for (int m = 0; m < 2; ++m)
                acc[m][1] = __builtin_amdgcn_mfma_f32_32x32x16_bf16(
                    af[m][ks], bf1[ks], acc[m][1], 0, 0, 0);
        __builtin_amdgcn_s_setprio(0);
        if (pfA) { STG(nA, pA[2], 2); STG(nA, pA[3], 3); }
        __builtin_amdgcn_s_barrier();   // all sB[p] readers retired -> STG-B ok

        // ---- P3: reload af(qm1) (serial); STG B q0,q1; MFMA -> acc[2..3][0]
#pragma unroll
        for (int m = 0; m < 2; ++m) {
            const int row = wm + 64 + m * 32 + r32;
#pragma unroll
            for (int ks = 0; ks < 4; ++ks)
                af[m][ks] = *(const bf16x8*)
                    &sA[p][row * 64 + (((ks * 2 + half) ^ (row & 7)) << 3)];
        }
        if (pfB) { STG(stB, pB[0], 0); STG(stB, pB[1], 1); }
        LGK0;
        __builtin_amdgcn_s_setprio(1);
#pragma unroll
        for (int ks = 0; ks < 4; ++ks)
#pragma unroll
            for (int m = 0; m < 2; ++m)
                acc[2 + m][0] = __builtin_amdgcn_mfma_f32_32x32x16_bf16(
                    af[m][ks], bf0[ks], acc[2 + m][0], 0, 0, 0);
        __builtin_amdgcn_s_setprio(0);

        // ---- P4: MFMA(af x bf1 -> acc[2..3][1]); STG B q2,q3; vmcnt; barrier
        __builtin_amdgcn_s_setprio(1);
#pragma unroll
        for (int ks = 0; ks < 4; ++ks)
#pragma unroll
            for (int m = 0; m < 2; ++m)
                acc[2 + m][1] = __builtin_amdgcn_mfma_f32_32x32x16_bf16(
                    af[m][ks], bf1[ks], acc[2 + m][1], 0, 0, 0);
        __builtin_amdgcn_s_setprio(0);
        if (pfB) { STG(stB, pB[2], 2); STG(stB, pB[3], 3); }
        // Boundary: drain A(kt+1)+B(kt+1); keep B(kt+2)'s 4 loads in flight.
        if (pfB) asm volatile("s_waitcnt vmcnt(4)" ::: "memory");
        else     asm volatile("s_waitcnt vmcnt(0)" ::: "memory");
        __builtin_amdgcn_s_barrier();

        // ---- Pb: boundary reads for kt+1 (af qm0 + bf0 from buf p^1)
        if (pfA) {
            const unsigned short* cA = sA[p ^ 1];
            const unsigned short* cB = sB[p ^ 1];
#pragma unroll
            for (int m = 0; m < 2; ++m) {
                const int row = wm + m * 32 + r32;
#pragma unroll
                for (int ks = 0; ks < 4; ++ks)
                    af[m][ks] = *(const bf16x8*)
                        &cA[row * 64 + (((ks * 2 + half) ^ (row & 7)) << 3)];
            }
            const int row = wn + r32;
#pragma unroll
            for (int ks = 0; ks < 4; ++ks)
                bf0[ks] = *(const bf16x8*)
                    &cB[row * 64 + (((ks * 2 + half) ^ (row & 7)) << 3)];
#pragma unroll
            for (int q = 0; q < 4; ++q) { pA[q] += 64; pB[q] += 64; }
        }
    }

    // ---- epilogue (32x32 C/D layout: col=lane&31, row=(r&3)+8*(r>>2)+4*half)
#pragma unroll
    for (int mb = 0; mb < 4; ++mb) {
        const int row_base = bm + wm + mb * 32;
#pragma unroll
        for (int nb = 0; nb < 2; ++nb) {
            const int col = bn + wn + nb * 32 + r32;
#pragma unroll
            for (int r = 0; r < 16; ++r) {
                const int row = row_base + (r & 3) + 8 * (r >> 2) + 4 * half;
                float v = acc[mb][nb][r];
                if (GELU) {
                    float t = 1.5957691216057308f * (v + 0.044715f * v * v * v);
                    v = v / (1.0f + __expf(-t));
                }
                if constexpr (sizeof(CT) == 2) {
                    ((unsigned short*)C)[(long long)row * N + col] = f2b(v);
                } else {
                    ((float*)C)[(long long)row * N + col] = v;
                }
            }
        }
    }
}
#undef STG
#undef LGK0

extern "C" void kernel_launch(void* const* d_in, const int* in_sizes, int n_in,
                              void* d_out, int out_size, void* d_ws, size_t ws_size,
                              hipStream_t stream) {
    constexpr int E = 8, T = 2048, H = 1024, F = 4096;
    const float* x  = (const float*)d_in[0];   // [E,T,H]
    const float* w1 = (const float*)d_in[1];   // [E,F,H]
    const float* w2 = (const float*)d_in[2];   // [E,F,H]
    float* out = (float*)d_out;                // [E,T,H]

    unsigned short* xb  = (unsigned short*)d_ws;          // E*T*H bf16
    unsigned short* w1b = xb  + (size_t)E * T * H;        // E*F*H bf16
    unsigned short* w2t = w1b + (size_t)E * F * H;        // E*H*F bf16 (transposed)
    unsigned short* ab  = w2t + (size_t)E * F * H;        // E*T*F bf16 (gelu act)

    const int nx = E * T * H / 4, nw = E * F * H / 4;
    cast2_f32_bf16<<<(nx + nw + 255) / 256, 256, 0, stream>>>(x, xb, nx, w1, w1b, nw);
    transpose_cast<<<dim3(H / 32, F / 64, E), dim3(32, 8), 0, stream>>>(w2, w2t, F, H);

    // GEMM1: a = gelu(x @ w1^T)   [M=T, N=F, K=H] -> bf16 (read-ahead 256^2)
    gemm_ra<true, unsigned short>
        <<<dim3(E * (T / 256) * (F / 256)), 512, 0, stream>>>(xb, w1b, ab, T, F, H);
    // GEMM2: out = a @ w2t^T      [M=T, N=H, K=F] -> fp32 (read-ahead 256^2)
    gemm_ra<false, float>
        <<<dim3(E * (T / 256) * (H / 256)), 512, 0, stream>>>(ab, w2t, out, T, H, F);
}